// Round 9
// baseline (46805.014 us; speedup 1.0000x reference)
//
#include <hip/hip_runtime.h>
#include <hip/hip_cooperative_groups.h>
#include <math.h>

// ---------------------------------------------------------------------------
// Decoder_21371757265153 — v9: persistent cooperative decoder.
// Same dataflow as v8 (PASSED, 7.39 ms): 16 seq x 16 row-slices, redundant
// scan, parity-double-buffered h, slice-private c. But one persistent
// cooperative kernel with grid.sync() per event instead of 1024 dispatches:
//  - scan state + c live in REGISTERS across events (no prologue reload)
//  - W_lin / label tables persist in LDS
//  - loop breaks when all sequences done (null rounds eliminated)
//  - cross-block h + done-counter via device-scope atomics
// Hang-proofing: hard cap 1100 iterations (>= worst-case events+1) => always
// terminates; if hipLaunchCooperativeKernel errors, fall back to the v8
// round loop (kept verbatim below, proven).
// ---------------------------------------------------------------------------

namespace cg = cooperative_groups;

namespace {
constexpr int NB = 16;
constexpr int NT = 1024;
constexpr int NE = 768;
constexpr int NH = 384;
constexpr int NL = 33;
constexpr int ROUNDS = 1024;
constexpr int NSLICE = 16;
constexpr int JS = 24;
constexpr int RS = 96;

constexpr size_t OFF_SL   = 0;                         // WS[sl][k][96]
constexpr size_t N_SL     = (size_t)NSLICE * NE * RS;  // 1179648
constexpr size_t OFF_PEW  = OFF_SL + N_SL;
constexpr size_t N_PEW    = 32 * NH;
constexpr size_t OFF_ENCW = OFF_PEW + N_PEW;
constexpr size_t N_ENCW   = (size_t)NB * NT * NL;
constexpr size_t OFF_BS   = OFF_ENCW + N_ENCW;
constexpr size_t OFF_PC   = OFF_BS + 2048;
constexpr size_t N_PC     = (size_t)NB * 1025 * NH;
constexpr size_t OFF_STATE = OFF_PC + N_PC;
constexpr size_t ST_STRIDE = 4096;
constexpr size_t OFF_FLG  = OFF_STATE + (size_t)NB * ST_STRIDE;
constexpr int SX_HWBP = 64;
constexpr int SX_H    = 1280;
constexpr int SX_C    = 2432;
constexpr int IX_T = 0, IX_WLEN = 1, IX_NW = 2, IX_NPOS = 3, IX_PLAST = 4,
              IX_LPEP = 5, IX_LPEE = 6, IX_DONE = 7;
}

__device__ __forceinline__ float sigmf(float x) { return 1.0f / (1.0f + expf(-x)); }
__device__ __forceinline__ float ldAf(const float* p) {
    return __hip_atomic_load(p, __ATOMIC_RELAXED, __HIP_MEMORY_SCOPE_AGENT);
}
__device__ __forceinline__ void stAf(float* p, float v) {
    __hip_atomic_store(p, v, __ATOMIC_RELAXED, __HIP_MEMORY_SCOPE_AGENT);
}

// ---- WS[sl][k][96] + posEmbW ----------------------------------------------
__global__ void k_prep(const float* __restrict__ W_ih, const float* __restrict__ W_hh,
                       const float* __restrict__ W_cmb, const float* __restrict__ posEmb,
                       float* __restrict__ ws) {
    float* SL = ws + OFF_SL;
    float* pw = ws + OFF_PEW;
    const int n1 = (int)N_SL, n2 = (int)N_PEW;
    for (int i = blockIdx.x * blockDim.x + threadIdx.x; i < n1 + n2;
         i += gridDim.x * blockDim.x) {
        if (i < n1) {
            int sl = i / (NE * RS), rem = i % (NE * RS);
            int k = rem / RS, rho = rem % RS;
            int gate = rho / JS, jj = rho % JS;
            int grow = gate * NH + sl * JS + jj;
            SL[i] = (k < NH) ? W_ih[(size_t)grow * NH + k]
                             : W_hh[(size_t)grow * NH + (k - NH)];
        } else {
            int j3 = i - n1;
            int p = j3 / NH, j = j3 % NH;
            const float* pe = posEmb + p * 128;
            const float* wr = W_cmb + (size_t)j * 896;
            float a = 0.f;
            #pragma unroll 4
            for (int k = 0; k < 128; ++k) a += pe[k] * wr[k];
            pw[j3] = a;
        }
    }
}

// ---- encW[bt][l] = enc[bt,:] @ W_lin[l, 384:] -----------------------------
__global__ void k_encw(const float* __restrict__ enc, const float* __restrict__ W_lin,
                       float* __restrict__ ws) {
    float* encW = ws + OFF_ENCW;
    int gid = blockIdx.x * 256 + threadIdx.x;
    if (gid >= NB * NT * NL) return;
    int bt = gid / NL, l = gid % NL;
    const float4* e4 = (const float4*)(enc + (size_t)bt * NE);
    const float4* w4 = (const float4*)(W_lin + (size_t)l * 1152 + NH);
    float a0 = 0, a1 = 0, a2 = 0, a3 = 0;
    for (int k = 0; k < NE / 4; ++k) {
        float4 e = e4[k], w = w4[k];
        a0 += e.x * w.x; a1 += e.y * w.y; a2 += e.z * w.z; a3 += e.w * w.w;
    }
    encW[gid] = (a0 + a1) + (a2 + a3);
}

// ---- pc[b][t][j] = enc[b,t,:] @ W_cmb[j,128:]  (pre-prefix) ---------------
__global__ void k_encCmb(const float* __restrict__ enc, const float* __restrict__ W_cmb,
                         float* __restrict__ ws) {
    __shared__ float tile[16][NE];
    float* pc = ws + OFF_PC;
    int blk = blockIdx.x;
    int b = blk >> 6;
    int t0 = (blk & 63) * 16;
    for (int i = threadIdx.x; i < 16 * NE; i += 384) {
        int row = i / NE, k = i % NE;
        tile[row][k] = enc[((size_t)(b * NT + t0 + row)) * NE + k];
    }
    __syncthreads();
    int j = threadIdx.x;
    const float4* w4 = (const float4*)(W_cmb + (size_t)j * 896 + 128);
    float acc[16];
    #pragma unroll
    for (int r = 0; r < 16; ++r) acc[r] = 0.f;
    for (int q = 0; q < NE / 4; ++q) {
        float4 w = w4[q];
        #pragma unroll
        for (int r = 0; r < 16; ++r) {
            acc[r] += w.x * tile[r][q * 4] + w.y * tile[r][q * 4 + 1]
                    + w.z * tile[r][q * 4 + 2] + w.w * tile[r][q * 4 + 3];
        }
    }
    #pragma unroll
    for (int r = 0; r < 16; ++r)
        pc[((size_t)b * 1025 + t0 + r) * NH + j] = acc[r];
}

// ---- in-place exclusive prefix over t per (b,j) ---------------------------
__global__ void k_prefix(float* __restrict__ ws) {
    float* pc = ws + OFF_PC;
    int id = blockIdx.x * 256 + threadIdx.x;
    if (id >= NB * NH) return;
    int b = id / NH, j = id % NH;
    float* p = pc + ((size_t)b * 1025) * NH + j;
    float s = 0.f;
    for (int t = 0; t < NT; ++t) {
        float x = p[(size_t)t * NH];
        p[(size_t)t * NH] = s;
        s += x;
    }
    p[(size_t)NT * NH] = s;
}

// ---- init: slot-0 state, bsum, done-counter -------------------------------
__global__ void k_init(const float* __restrict__ b_ih, const float* __restrict__ b_hh,
                       const float* __restrict__ W_lin, const float* __restrict__ b_lin,
                       float* __restrict__ ws) {
    __shared__ float shh[NH], shc[NH], shw[NL];
    int tid = threadIdx.x;
    if (tid < NH) {
        float gi = b_ih[tid] + b_hh[tid];
        float gg = b_ih[2 * NH + tid] + b_hh[2 * NH + tid];
        float go = b_ih[3 * NH + tid] + b_hh[3 * NH + tid];
        float c = sigmf(gi) * tanhf(gg);
        float h = sigmf(go) * tanhf(c);
        shh[tid] = h; shc[tid] = c;
    }
    __syncthreads();
    if (tid < NL) {
        float a = b_lin[tid];
        for (int k = 0; k < NH; ++k) a += W_lin[(size_t)tid * 1152 + k] * shh[k];
        shw[tid] = a;
    }
    for (int i = tid; i < 4 * NH; i += 1024) ws[OFF_BS + i] = b_ih[i] + b_hh[i];
    __syncthreads();
    for (int s = 0; s < NB; ++s) {
        float* stf = ws + OFF_STATE + (size_t)s * ST_STRIDE;
        int* ii = (int*)stf;
        if (tid < 16) ii[tid] = (tid == IX_LPEP || tid == IX_LPEE) ? -1 : 0;
        if (tid >= 32 && tid < 32 + 576) {
            int i2 = tid - 32, r = i2 / 36, l = i2 % 36;
            stf[SX_HWBP + i2] = (r == 0 && l < NL) ? (shw[l] - b_lin[l]) : 0.f;
        }
        if (tid < NH) { stf[SX_H + tid] = shh[tid]; stf[SX_C + tid] = shc[tid]; }
    }
    if (tid == 0) *(int*)(ws + OFF_FLG) = 0;
}

// ---- zero output ----------------------------------------------------------
__global__ void k_fill(float* __restrict__ out) {
    int i = blockIdx.x * 256 + threadIdx.x;
    if (i < NB * NT * NL) out[i] = 0.f;
}

// ---- v9: persistent cooperative decoder -----------------------------------
__global__ __launch_bounds__(384) void k_coop(
    const int* __restrict__ char_sizes,
    const int* __restrict__ label_is_sep, const int* __restrict__ label_pos_id,
    const float* __restrict__ W_lin, const float* __restrict__ b_lin,
    const float* __restrict__ b_cmb, float* __restrict__ ws,
    float* __restrict__ out) {

    cg::grid_group grid = cg::this_grid();

    const int bid = blockIdx.x;
    const int s = bid >> 4;        // sequence
    const int rh = bid & 15;       // row-slice
    const int tid = threadIdx.x;
    const int lane = tid & 63;
    const int wave = tid >> 6;

    float* stf  = ws + OFF_STATE + (size_t)s * ST_STRIDE;
    float* h_ws = stf + SX_H;                 // 2 slots x 512
    int* cnt = (int*)(ws + OFF_FLG);

    const float* SLw  = ws + OFF_SL + (size_t)rh * (NE * RS);
    const float* pew  = ws + OFF_PEW;
    const float* bsum = ws + OFF_BS;
    const float* pcb  = ws + OFF_PC + (size_t)s * 1025 * NH;
    const float* eWb  = ws + OFF_ENCW + (size_t)s * NT * NL;
    float* outb = out + (size_t)s * NT * NL;

    __shared__ float sh_Wlin[NL * NH];        // 50688 B, persistent
    __shared__ float sh_x[NE], sh_h[NH], sh_part[384], sh_g[RS], sh_red[264], sh_hWb[40];
    __shared__ int sh_issep[NL], sh_posid[NL], sh_ctl[2];

    for (int i = tid; i < NL * NH; i += 384) {
        int l = i / NH, k = i - l * NH;
        sh_Wlin[i] = W_lin[(size_t)l * 1152 + k];
    }
    if (tid < NL) { sh_issep[tid] = label_is_sep[tid]; sh_posid[tid] = label_pos_id[tid]; }
    float creg = (tid < JS) ? stf[SX_C + rh * JS + tid] : 0.f;
    int size = char_sizes[s]; if (size > NT) size = NT;
    int t = 0, wlen = 0, nw = 0, npos = 0, plast = 0, lpe_pend = -1, lpe_eff = -1;
    int my_done = 0;
    __syncthreads();

    for (int iter = 0; iter < 1100; ++iter) {     // hard bound: always terminates
        if (!my_done) {
            const int slot_r = iter & 1, slot_w = slot_r ^ 1;
            sh_h[tid] = ldAf(h_ws + slot_r * 512 + tid);   // agent-coherent h read
            __syncthreads();
            if (tid < 264) {
                const int l = tid >> 3, p = tid & 7;
                const float* wr = sh_Wlin + l * NH + p * 48;
                const float* hp = sh_h + p * 48;
                float a = 0.f;
                #pragma unroll
                for (int k = 0; k < 48; ++k) a += wr[k] * hp[k];
                sh_red[tid] = a;
            }
            __syncthreads();
            if (tid < NL) {
                float q = b_lin[tid];
                #pragma unroll
                for (int p = 0; p < 8; ++p) q += sh_red[tid * 8 + p];
                sh_hWb[tid] = q;
            }
            __syncthreads();

            // ---- scan (redundant in all blocks/waves; deterministic) ----
            int evt_t = -1, evt_start = 0; float evt_den = 1.f;
            for (; t < size; ++t) {
                float ot = (lane < NL) ? tanhf(eWb[(size_t)t * NL + lane] + sh_hWb[lane]) : -INFINITY;
                float bv = ot; int bi = lane;
                #pragma unroll
                for (int d = 32; d; d >>= 1) {
                    float ov = __shfl_xor(bv, d);
                    int   oi = __shfl_xor(bi, d);
                    if (ov > bv || (ov == bv && oi < bi)) { bv = ov; bi = oi; }
                }
                const int aid = bi;
                if (rh == 0 && wave == 0 && lane < NL) outb[(size_t)t * NL + lane] = ot;
                const int issep = sh_issep[aid];
                const int wl_prev = wlen;
                int nw_new;
                if (issep) { npos += 1; nw_new = nw + 1; }
                else       { nw_new = (nw < 1) ? 1 : nw; }
                const int do_l = issep && (nw_new >= 2);
                if (issep && npos >= 2) lpe_pend = plast;
                if (issep) plast = sh_posid[aid];
                wlen = issep ? 1 : wlen + 1;
                nw = nw_new;
                if (do_l) {
                    evt_t = t;
                    evt_start = (t - wl_prev < 0) ? 0 : (t - wl_prev);
                    evt_den = (float)((wl_prev < 1) ? 1 : wl_prev);
                    if (lpe_pend >= 0) { lpe_eff = lpe_pend; lpe_pend = -1; }
                    ++t;
                    break;
                }
            }

            if (evt_t < 0) {
                my_done = 1;
                if (rh == 0 && tid == 0)
                    __hip_atomic_fetch_add(cnt, 1, __ATOMIC_RELAXED, __HIP_MEMORY_SCOPE_AGENT);
            } else {
                // xcat = [tanh(pv + avg + b_cmb), h]
                {
                    const int j = tid;
                    float avg = (pcb[(size_t)evt_t * NH + j] - pcb[(size_t)evt_start * NH + j]) / evt_den;
                    float pv = (lpe_eff >= 0) ? pew[lpe_eff * NH + j] : 0.f;
                    sh_x[j]      = tanhf(pv + avg + b_cmb[j]);
                    sh_x[NH + j] = sh_h[j];
                }
                __syncthreads();
                // matvec own 96-row slice (L2-resident)
                {
                    const int rho = tid % RS, kq = tid / RS;
                    const float* wp = SLw + (size_t)(kq * 192) * RS + rho;
                    const float* xp = sh_x + kq * 192;
                    float a0 = 0.f, a1 = 0.f, a2 = 0.f, a3 = 0.f;
                    #pragma unroll 8
                    for (int k = 0; k < 192; k += 4) {
                        a0 += wp[(size_t)(k + 0) * RS] * xp[k + 0];
                        a1 += wp[(size_t)(k + 1) * RS] * xp[k + 1];
                        a2 += wp[(size_t)(k + 2) * RS] * xp[k + 2];
                        a3 += wp[(size_t)(k + 3) * RS] * xp[k + 3];
                    }
                    sh_part[tid] = (a0 + a1) + (a2 + a3);
                }
                __syncthreads();
                if (tid < RS) {
                    const int gate = tid / JS, jj = tid % JS;
                    const int grow = gate * NH + rh * JS + jj;
                    sh_g[tid] = ((sh_part[tid] + sh_part[RS + tid])
                               + (sh_part[2 * RS + tid] + sh_part[3 * RS + tid])) + bsum[grow];
                }
                __syncthreads();
                if (tid < JS) {
                    float gi = sh_g[tid], gf = sh_g[JS + tid];
                    float gg = sh_g[2 * JS + tid], go = sh_g[3 * JS + tid];
                    float c2 = sigmf(gf) * creg + sigmf(gi) * tanhf(gg);
                    float h2 = sigmf(go) * tanhf(c2);
                    creg = c2;
                    stAf(h_ws + slot_w * 512 + rh * JS + tid, h2);
                }
            }
        }
        __threadfence();
        grid.sync();
        __threadfence();
        if (tid == 0)
            sh_ctl[0] = __hip_atomic_load(cnt, __ATOMIC_RELAXED, __HIP_MEMORY_SCOPE_AGENT);
        __syncthreads();
        if (sh_ctl[0] >= NB) break;
    }
}

// ---- v8 fallback: one-dispatch-per-event round kernel (proven) ------------
__global__ __launch_bounds__(384) void k_round(
    const int* __restrict__ char_sizes,
    const int* __restrict__ label_is_sep, const int* __restrict__ label_pos_id,
    const float* __restrict__ W_lin, const float* __restrict__ b_lin,
    const float* __restrict__ b_cmb, float* __restrict__ ws,
    float* __restrict__ out, const int slot) {

    const int bid = blockIdx.x;
    const int s = bid >> 4;
    const int rh = bid & 15;
    const int tid = threadIdx.x;
    const int lane = tid & 63;
    const int wave = tid >> 6;

    float* stf = ws + OFF_STATE + (size_t)s * ST_STRIDE;
    int* ir = (int*)stf + slot * 16;
    int* iw = (int*)stf + (slot ^ 1) * 16;
    if (ir[IX_DONE]) return;

    const float* hWbp_r = stf + SX_HWBP + slot * 576;
    float*       hWbp_w = stf + SX_HWBP + (slot ^ 1) * 576;
    const float* h_r    = stf + SX_H + slot * 512;
    float*       h_w    = stf + SX_H + (slot ^ 1) * 512;
    float*       cst    = stf + SX_C;

    const float* SLw  = ws + OFF_SL + (size_t)rh * (NE * RS);
    const float* pew  = ws + OFF_PEW;
    const float* encW = ws + OFF_ENCW;
    const float* bsum = ws + OFF_BS;
    const float* pcb  = ws + OFF_PC + (size_t)s * 1025 * NH;

    __shared__ float sh_hWb[40], sh_h[NH], sh_x[NE], sh_part[384], sh_g[RS], sh_h2[JS];
    __shared__ int sh_issep[NL], sh_posid[NL];

    if (tid < NL) {
        float a = b_lin[tid];
        #pragma unroll
        for (int i = 0; i < 16; ++i) a += hWbp_r[i * 36 + tid];
        sh_hWb[tid] = a;
        sh_issep[tid] = label_is_sep[tid];
        sh_posid[tid] = label_pos_id[tid];
    }
    sh_h[tid % NH] = h_r[tid % NH];
    float creg = (tid < JS) ? cst[rh * JS + tid] : 0.f;
    __syncthreads();

    int t = ir[IX_T], wlen = ir[IX_WLEN], nw = ir[IX_NW], npos = ir[IX_NPOS],
        plast = ir[IX_PLAST], lpe_pend = ir[IX_LPEP], lpe_eff = ir[IX_LPEE];
    int size = char_sizes[s]; if (size > NT) size = NT;
    const float* eWb = encW + (size_t)s * NT * NL;
    float* outb = out + (size_t)s * NT * NL;
    int evt_t = -1, evt_start = 0; float evt_den = 1.f;

    for (; t < size; ++t) {
        float ot = (lane < NL) ? tanhf(eWb[(size_t)t * NL + lane] + sh_hWb[lane]) : -INFINITY;
        float bv = ot; int bi = lane;
        #pragma unroll
        for (int d = 32; d; d >>= 1) {
            float ov = __shfl_xor(bv, d);
            int   oi = __shfl_xor(bi, d);
            if (ov > bv || (ov == bv && oi < bi)) { bv = ov; bi = oi; }
        }
        const int aid = bi;
        if (rh == 0 && wave == 0 && lane < NL) outb[(size_t)t * NL + lane] = ot;
        const int issep = sh_issep[aid];
        const int wl_prev = wlen;
        int nw_new;
        if (issep) { npos += 1; nw_new = nw + 1; }
        else       { nw_new = (nw < 1) ? 1 : nw; }
        const int do_l = issep && (nw_new >= 2);
        if (issep && npos >= 2) lpe_pend = plast;
        if (issep) plast = sh_posid[aid];
        wlen = issep ? 1 : wlen + 1;
        nw = nw_new;
        if (do_l) {
            evt_t = t;
            evt_start = (t - wl_prev < 0) ? 0 : (t - wl_prev);
            evt_den = (float)((wl_prev < 1) ? 1 : wl_prev);
            if (lpe_pend >= 0) { lpe_eff = lpe_pend; lpe_pend = -1; }
            ++t;
            break;
        }
    }

    if (evt_t < 0) {
        if (rh == 0 && tid == 0) { iw[IX_DONE] = 1; ir[IX_DONE] = 1; }
        return;
    }

    {
        const int j = tid;
        float avg = (pcb[(size_t)evt_t * NH + j] - pcb[(size_t)evt_start * NH + j]) / evt_den;
        float pv = (lpe_eff >= 0) ? pew[lpe_eff * NH + j] : 0.f;
        sh_x[j]      = tanhf(pv + avg + b_cmb[j]);
        sh_x[NH + j] = sh_h[j];
    }
    __syncthreads();
    {
        const int rho = tid % RS, kq = tid / RS;
        const float* wp = SLw + (size_t)(kq * 192) * RS + rho;
        const float* xp = sh_x + kq * 192;
        float a0 = 0.f, a1 = 0.f, a2 = 0.f, a3 = 0.f;
        #pragma unroll 8
        for (int k = 0; k < 192; k += 4) {
            a0 += wp[(size_t)(k + 0) * RS] * xp[k + 0];
            a1 += wp[(size_t)(k + 1) * RS] * xp[k + 1];
            a2 += wp[(size_t)(k + 2) * RS] * xp[k + 2];
            a3 += wp[(size_t)(k + 3) * RS] * xp[k + 3];
        }
        sh_part[tid] = (a0 + a1) + (a2 + a3);
    }
    __syncthreads();
    if (tid < RS) {
        const int gate = tid / JS, jj = tid % JS;
        const int grow = gate * NH + rh * JS + jj;
        sh_g[tid] = ((sh_part[tid] + sh_part[RS + tid])
                   + (sh_part[2 * RS + tid] + sh_part[3 * RS + tid])) + bsum[grow];
    }
    __syncthreads();
    if (tid < JS) {
        float gi = sh_g[tid], gf = sh_g[JS + tid], gg = sh_g[2 * JS + tid], go = sh_g[3 * JS + tid];
        float c2 = sigmf(gf) * creg + sigmf(gi) * tanhf(gg);
        float h2 = sigmf(go) * tanhf(c2);
        cst[rh * JS + tid] = c2;
        h_w[rh * JS + tid] = h2;
        sh_h2[tid] = h2;
    }
    __syncthreads();
    if (tid < NL) {
        const float* wr = W_lin + (size_t)tid * 1152 + rh * JS;
        float a = 0.f;
        #pragma unroll
        for (int k = 0; k < JS; ++k) a += wr[k] * sh_h2[k];
        hWbp_w[rh * 36 + tid] = a;
    }
    if (rh == 0 && tid == 0) {
        iw[IX_T] = t; iw[IX_WLEN] = wlen; iw[IX_NW] = nw; iw[IX_NPOS] = npos;
        iw[IX_PLAST] = plast; iw[IX_LPEP] = lpe_pend; iw[IX_LPEE] = lpe_eff;
        iw[IX_DONE] = 0;
    }
}

// ---- parallel log-softmax -------------------------------------------------
__global__ void k_post(float* __restrict__ out) {
    int row = blockIdx.x * 4 + (threadIdx.x >> 6);
    int lane = threadIdx.x & 63;
    if (row >= NB * NT) return;
    float* p = out + (size_t)row * NL;
    float x = (lane < NL) ? p[lane] : -INFINITY;
    float m = x;
    #pragma unroll
    for (int d = 32; d; d >>= 1) m = fmaxf(m, __shfl_xor(m, d));
    float e = (lane < NL) ? expf(x - m) : 0.f;
    float su = e;
    #pragma unroll
    for (int d = 32; d; d >>= 1) su += __shfl_xor(su, d);
    if (lane < NL) p[lane] = (x - m) - logf(su);
}

extern "C" void kernel_launch(void* const* d_in, const int* in_sizes, int n_in,
                              void* d_out, int out_size, void* d_ws, size_t ws_size,
                              hipStream_t stream) {
    const float* enc          = (const float*)d_in[0];
    const int*   char_sizes   = (const int*)d_in[1];
    const int*   label_is_sep = (const int*)d_in[2];
    const int*   label_pos_id = (const int*)d_in[3];
    const float* posEmb       = (const float*)d_in[4];
    const float* W_ih         = (const float*)d_in[5];
    const float* W_hh         = (const float*)d_in[6];
    const float* b_ih         = (const float*)d_in[7];
    const float* b_hh         = (const float*)d_in[8];
    const float* W_lin        = (const float*)d_in[9];
    const float* b_lin        = (const float*)d_in[10];
    const float* W_cmb        = (const float*)d_in[11];
    const float* b_cmb        = (const float*)d_in[12];
    float* out = (float*)d_out;
    float* ws  = (float*)d_ws;

    hipLaunchKernelGGL(k_prep, dim3(1024), dim3(256), 0, stream,
                       W_ih, W_hh, W_cmb, posEmb, ws);
    hipLaunchKernelGGL(k_encw, dim3((NB * NT * NL + 255) / 256), dim3(256), 0, stream,
                       enc, W_lin, ws);
    hipLaunchKernelGGL(k_encCmb, dim3(1024), dim3(384), 0, stream, enc, W_cmb, ws);
    hipLaunchKernelGGL(k_prefix, dim3((NB * NH + 255) / 256), dim3(256), 0, stream, ws);
    hipLaunchKernelGGL(k_init, dim3(1), dim3(1024), 0, stream,
                       b_ih, b_hh, W_lin, b_lin, ws);
    hipLaunchKernelGGL(k_fill, dim3((NB * NT * NL + 255) / 256), dim3(256), 0, stream, out);

    void* args[] = {
        (void*)&char_sizes, (void*)&label_is_sep, (void*)&label_pos_id,
        (void*)&W_lin, (void*)&b_lin, (void*)&b_cmb, (void*)&ws, (void*)&out
    };
    hipError_t ce = hipLaunchCooperativeKernel((void*)k_coop, dim3(256), dim3(384),
                                               args, 0, stream);
    if (ce != hipSuccess) {
        // proven v8 path: one dispatch per worst-case event
        for (int r = 0; r < ROUNDS; ++r) {
            hipLaunchKernelGGL(k_round, dim3(256), dim3(384), 0, stream,
                               char_sizes, label_is_sep, label_pos_id,
                               W_lin, b_lin, b_cmb, ws, out, r & 1);
        }
    }

    hipLaunchKernelGGL(k_post, dim3((NB * NT + 3) / 4), dim3(256), 0, stream, out);
}

// Round 10
// 6903.663 us; speedup vs baseline: 6.7797x; 6.7797x over previous
//
#include <hip/hip_runtime.h>
#include <math.h>

// ---------------------------------------------------------------------------
// Decoder_21371757265153 — v10: round decoder (v8 skeleton) with intra-round
// overlap. Measured facts driving this design:
//  - v8 (1024 dispatches, kernel-boundary sync): 7.39 ms  [PASSED]
//  - v9 (cooperative grid.sync): 45.7 ms, VALU 1%  => grid.sync ~60-90 us on
//    MI355X with 256 blocks. Kernel boundary (~2.1 us) is the cheapest
//    grid-wide barrier. Custom spin protocols: 3 timeouts, abandoned.
// v10 change inside each active round:
//  - wave 0 runs the scan ALONE; waves 1-5 concurrently stream the W_hh*h
//    half-matvec (k in [384,768), 147 KB) which is scan-independent.
//  - after scan broadcast, all 384 threads stream only the x-half (147 KB).
//  => matvec contribution to critical path 2.2 -> ~1.1 us.
// Everything else (state layout, parity double-buffer, precompute) = v8.
// ---------------------------------------------------------------------------

namespace {
constexpr int NB = 16;
constexpr int NT = 1024;
constexpr int NE = 768;
constexpr int NH = 384;
constexpr int NL = 33;
constexpr int ROUNDS = 1024;
constexpr int NSLICE = 16;
constexpr int JS = 24;
constexpr int RS = 96;

constexpr size_t OFF_SL   = 0;                         // WS[sl][k][96]
constexpr size_t N_SL     = (size_t)NSLICE * NE * RS;  // 1179648
constexpr size_t OFF_PEW  = OFF_SL + N_SL;
constexpr size_t N_PEW    = 32 * NH;
constexpr size_t OFF_ENCW = OFF_PEW + N_PEW;
constexpr size_t N_ENCW   = (size_t)NB * NT * NL;
constexpr size_t OFF_BS   = OFF_ENCW + N_ENCW;
constexpr size_t OFF_PC   = OFF_BS + 2048;
constexpr size_t N_PC     = (size_t)NB * 1025 * NH;
constexpr size_t OFF_STATE = OFF_PC + N_PC;
constexpr size_t ST_STRIDE = 4096;
constexpr int SX_HWBP = 64;    // 2 slots x [16][36]
constexpr int SX_H    = 1280;  // 2 slots x 512
constexpr int SX_C    = 2432;  // 384
constexpr int IX_T = 0, IX_WLEN = 1, IX_NW = 2, IX_NPOS = 3, IX_PLAST = 4,
              IX_LPEP = 5, IX_LPEE = 6, IX_DONE = 7;
}

__device__ __forceinline__ float sigmf(float x) { return 1.0f / (1.0f + expf(-x)); }

// ---- WS[sl][k][96] + posEmbW ----------------------------------------------
__global__ void k_prep(const float* __restrict__ W_ih, const float* __restrict__ W_hh,
                       const float* __restrict__ W_cmb, const float* __restrict__ posEmb,
                       float* __restrict__ ws) {
    float* SL = ws + OFF_SL;
    float* pw = ws + OFF_PEW;
    const int n1 = (int)N_SL, n2 = (int)N_PEW;
    for (int i = blockIdx.x * blockDim.x + threadIdx.x; i < n1 + n2;
         i += gridDim.x * blockDim.x) {
        if (i < n1) {
            int sl = i / (NE * RS), rem = i % (NE * RS);
            int k = rem / RS, rho = rem % RS;
            int gate = rho / JS, jj = rho % JS;
            int grow = gate * NH + sl * JS + jj;
            SL[i] = (k < NH) ? W_ih[(size_t)grow * NH + k]
                             : W_hh[(size_t)grow * NH + (k - NH)];
        } else {
            int j3 = i - n1;
            int p = j3 / NH, j = j3 % NH;
            const float* pe = posEmb + p * 128;
            const float* wr = W_cmb + (size_t)j * 896;
            float a = 0.f;
            #pragma unroll 4
            for (int k = 0; k < 128; ++k) a += pe[k] * wr[k];
            pw[j3] = a;
        }
    }
}

// ---- encW[bt][l] = enc[bt,:] @ W_lin[l, 384:] -----------------------------
__global__ void k_encw(const float* __restrict__ enc, const float* __restrict__ W_lin,
                       float* __restrict__ ws) {
    float* encW = ws + OFF_ENCW;
    int gid = blockIdx.x * 256 + threadIdx.x;
    if (gid >= NB * NT * NL) return;
    int bt = gid / NL, l = gid % NL;
    const float4* e4 = (const float4*)(enc + (size_t)bt * NE);
    const float4* w4 = (const float4*)(W_lin + (size_t)l * 1152 + NH);
    float a0 = 0, a1 = 0, a2 = 0, a3 = 0;
    for (int k = 0; k < NE / 4; ++k) {
        float4 e = e4[k], w = w4[k];
        a0 += e.x * w.x; a1 += e.y * w.y; a2 += e.z * w.z; a3 += e.w * w.w;
    }
    encW[gid] = (a0 + a1) + (a2 + a3);
}

// ---- pc[b][t][j] = enc[b,t,:] @ W_cmb[j,128:]  (pre-prefix) ---------------
__global__ void k_encCmb(const float* __restrict__ enc, const float* __restrict__ W_cmb,
                         float* __restrict__ ws) {
    __shared__ float tile[16][NE];
    float* pc = ws + OFF_PC;
    int blk = blockIdx.x;
    int b = blk >> 6;
    int t0 = (blk & 63) * 16;
    for (int i = threadIdx.x; i < 16 * NE; i += 384) {
        int row = i / NE, k = i % NE;
        tile[row][k] = enc[((size_t)(b * NT + t0 + row)) * NE + k];
    }
    __syncthreads();
    int j = threadIdx.x;
    const float4* w4 = (const float4*)(W_cmb + (size_t)j * 896 + 128);
    float acc[16];
    #pragma unroll
    for (int r = 0; r < 16; ++r) acc[r] = 0.f;
    for (int q = 0; q < NE / 4; ++q) {
        float4 w = w4[q];
        #pragma unroll
        for (int r = 0; r < 16; ++r) {
            acc[r] += w.x * tile[r][q * 4] + w.y * tile[r][q * 4 + 1]
                    + w.z * tile[r][q * 4 + 2] + w.w * tile[r][q * 4 + 3];
        }
    }
    #pragma unroll
    for (int r = 0; r < 16; ++r)
        pc[((size_t)b * 1025 + t0 + r) * NH + j] = acc[r];
}

// ---- in-place exclusive prefix over t per (b,j) ---------------------------
__global__ void k_prefix(float* __restrict__ ws) {
    float* pc = ws + OFF_PC;
    int id = blockIdx.x * 256 + threadIdx.x;
    if (id >= NB * NH) return;
    int b = id / NH, j = id % NH;
    float* p = pc + ((size_t)b * 1025) * NH + j;
    float s = 0.f;
    for (int t = 0; t < NT; ++t) {
        float x = p[(size_t)t * NH];
        p[(size_t)t * NH] = s;
        s += x;
    }
    p[(size_t)NT * NH] = s;
}

// ---- init: slot-0 state, bsum ---------------------------------------------
__global__ void k_init(const float* __restrict__ b_ih, const float* __restrict__ b_hh,
                       const float* __restrict__ W_lin, const float* __restrict__ b_lin,
                       float* __restrict__ ws) {
    __shared__ float shh[NH], shc[NH], shw[NL];
    int tid = threadIdx.x;
    if (tid < NH) {
        float gi = b_ih[tid] + b_hh[tid];
        float gg = b_ih[2 * NH + tid] + b_hh[2 * NH + tid];
        float go = b_ih[3 * NH + tid] + b_hh[3 * NH + tid];
        float c = sigmf(gi) * tanhf(gg);
        float h = sigmf(go) * tanhf(c);
        shh[tid] = h; shc[tid] = c;
    }
    __syncthreads();
    if (tid < NL) {
        float a = b_lin[tid];
        for (int k = 0; k < NH; ++k) a += W_lin[(size_t)tid * 1152 + k] * shh[k];
        shw[tid] = a;
    }
    for (int i = tid; i < 4 * NH; i += 1024) ws[OFF_BS + i] = b_ih[i] + b_hh[i];
    __syncthreads();
    for (int s = 0; s < NB; ++s) {
        float* stf = ws + OFF_STATE + (size_t)s * ST_STRIDE;
        int* ii = (int*)stf;
        if (tid < 16) ii[tid] = (tid == IX_LPEP || tid == IX_LPEE) ? -1 : 0;
        if (tid >= 32 && tid < 32 + 576) {
            int i2 = tid - 32, r = i2 / 36, l = i2 % 36;
            stf[SX_HWBP + i2] = (r == 0 && l < NL) ? (shw[l] - b_lin[l]) : 0.f;
        }
        if (tid < NH) { stf[SX_H + tid] = shh[tid]; stf[SX_C + tid] = shc[tid]; }
    }
}

// ---- zero output ----------------------------------------------------------
__global__ void k_fill(float* __restrict__ out) {
    int i = blockIdx.x * 256 + threadIdx.x;
    if (i < NB * NT * NL) out[i] = 0.f;
}

// ---- k_round v10: scan (wave 0) overlapped with W_hh*h half-matvec --------
__global__ __launch_bounds__(384) void k_round(
    const int* __restrict__ char_sizes,
    const int* __restrict__ label_is_sep, const int* __restrict__ label_pos_id,
    const float* __restrict__ W_lin, const float* __restrict__ b_lin,
    const float* __restrict__ b_cmb, float* __restrict__ ws,
    float* __restrict__ out, const int slot) {

    const int bid = blockIdx.x;
    const int s = bid >> 4;
    const int rh = bid & 15;
    const int tid = threadIdx.x;
    const int lane = tid & 63;
    const int wave = tid >> 6;

    float* stf = ws + OFF_STATE + (size_t)s * ST_STRIDE;
    int* ir = (int*)stf + slot * 16;
    int* iw = (int*)stf + (slot ^ 1) * 16;
    if (ir[IX_DONE]) return;

    const float* hWbp_r = stf + SX_HWBP + slot * 576;
    float*       hWbp_w = stf + SX_HWBP + (slot ^ 1) * 576;
    const float* h_r    = stf + SX_H + slot * 512;
    float*       h_w    = stf + SX_H + (slot ^ 1) * 512;
    float*       cst    = stf + SX_C;

    const float* SLw  = ws + OFF_SL + (size_t)rh * (NE * RS);
    const float* pew  = ws + OFF_PEW;
    const float* encW = ws + OFF_ENCW;
    const float* bsum = ws + OFF_BS;
    const float* pcb  = ws + OFF_PC + (size_t)s * 1025 * NH;

    __shared__ float sh_hWb[40], sh_h[NH], sh_x[NH], sh_part[384], sh_ph[288];
    __shared__ float sh_g[RS], sh_h2[JS];
    __shared__ int sh_issep[NL], sh_posid[NL], sh_scan[8];

    // prologue: h into LDS (needed by h-half waves), c into registers
    sh_h[tid] = h_r[tid];
    float creg = (tid < JS) ? cst[rh * JS + tid] : 0.f;
    __syncthreads();

    if (wave == 0) {
        // ---- wave 0: tables + hWb + scan (wave-coherent LDS use) ----
        if (lane < NL) {
            sh_issep[lane] = label_is_sep[lane];
            sh_posid[lane] = label_pos_id[lane];
            float a = b_lin[lane];
            #pragma unroll
            for (int i = 0; i < 16; ++i) a += hWbp_r[i * 36 + lane];
            sh_hWb[lane] = a;
        }
        asm volatile("" ::: "memory");   // keep LDS writes before reads (same wave)

        int t = ir[IX_T], wlen = ir[IX_WLEN], nw = ir[IX_NW], npos = ir[IX_NPOS],
            plast = ir[IX_PLAST], lpe_pend = ir[IX_LPEP], lpe_eff = ir[IX_LPEE];
        int size = char_sizes[s]; if (size > NT) size = NT;
        const float* eWb = encW + (size_t)s * NT * NL;
        float* outb = out + (size_t)s * NT * NL;
        int evt_t = -1, evt_start = 0; float evt_den = 1.f;

        for (; t < size; ++t) {
            float ot = (lane < NL) ? tanhf(eWb[(size_t)t * NL + lane] + sh_hWb[lane]) : -INFINITY;
            float bv = ot; int bi = lane;
            #pragma unroll
            for (int d = 32; d; d >>= 1) {
                float ov = __shfl_xor(bv, d);
                int   oi = __shfl_xor(bi, d);
                if (ov > bv || (ov == bv && oi < bi)) { bv = ov; bi = oi; }
            }
            const int aid = bi;
            if (rh == 0 && lane < NL) outb[(size_t)t * NL + lane] = ot;
            const int issep = sh_issep[aid];
            const int wl_prev = wlen;
            int nw_new;
            if (issep) { npos += 1; nw_new = nw + 1; }
            else       { nw_new = (nw < 1) ? 1 : nw; }
            const int do_l = issep && (nw_new >= 2);
            if (issep && npos >= 2) lpe_pend = plast;
            if (issep) plast = sh_posid[aid];
            wlen = issep ? 1 : wlen + 1;
            nw = nw_new;
            if (do_l) {
                evt_t = t;
                evt_start = (t - wl_prev < 0) ? 0 : (t - wl_prev);
                evt_den = (float)((wl_prev < 1) ? 1 : wl_prev);
                if (lpe_pend >= 0) { lpe_eff = lpe_pend; lpe_pend = -1; }
                ++t;
                break;
            }
        }

        if (lane == 0) {
            sh_scan[0] = evt_t; sh_scan[1] = evt_start;
            sh_scan[2] = __float_as_int(evt_den); sh_scan[3] = lpe_eff;
            if (rh == 0) {
                if (evt_t < 0) {
                    iw[IX_DONE] = 1; ir[IX_DONE] = 1;
                } else {
                    iw[IX_T] = t; iw[IX_WLEN] = wlen; iw[IX_NW] = nw;
                    iw[IX_NPOS] = npos; iw[IX_PLAST] = plast;
                    iw[IX_LPEP] = lpe_pend; iw[IX_LPEE] = lpe_eff;
                    iw[IX_DONE] = 0;
                }
            }
        }
    } else if (tid >= 64 && tid < 352) {
        // ---- waves 1-5: W_hh * h half-matvec (scan-independent, 147 KB) ----
        const int u = tid - 64;
        const int ci = u / 96, rho = u - ci * 96;     // 3 k-chunks x 96 rows
        const float* wp = SLw + (size_t)(NH + ci * 128) * RS + rho;
        const float* xp = sh_h + ci * 128;
        float a0 = 0.f, a1 = 0.f, a2 = 0.f, a3 = 0.f;
        #pragma unroll 8
        for (int k = 0; k < 128; k += 4) {
            a0 += wp[(size_t)(k + 0) * RS] * xp[k + 0];
            a1 += wp[(size_t)(k + 1) * RS] * xp[k + 1];
            a2 += wp[(size_t)(k + 2) * RS] * xp[k + 2];
            a3 += wp[(size_t)(k + 3) * RS] * xp[k + 3];
        }
        sh_ph[ci * 96 + rho] = (a0 + a1) + (a2 + a3);
    }
    __syncthreads();

    const int evt_t = sh_scan[0];
    if (evt_t < 0) return;
    const int evt_start = sh_scan[1];
    const float evt_den = __int_as_float(sh_scan[2]);
    const int lpe_eff = sh_scan[3];

    // ---- xcat lwp half (h half not needed — folded into sh_ph) ----
    {
        const int j = tid;
        float avg = (pcb[(size_t)evt_t * NH + j] - pcb[(size_t)evt_start * NH + j]) / evt_den;
        float pv = (lpe_eff >= 0) ? pew[lpe_eff * NH + j] : 0.f;
        sh_x[j] = tanhf(pv + avg + b_cmb[j]);
    }
    __syncthreads();

    // ---- x-half matvec: 4 k-chunks x 96 rows (147 KB) ----
    {
        const int kq = tid / 96, rho = tid - kq * 96;
        const float* wp = SLw + (size_t)(kq * 96) * RS + rho;
        const float* xp = sh_x + kq * 96;
        float a0 = 0.f, a1 = 0.f, a2 = 0.f, a3 = 0.f;
        #pragma unroll 8
        for (int k = 0; k < 96; k += 4) {
            a0 += wp[(size_t)(k + 0) * RS] * xp[k + 0];
            a1 += wp[(size_t)(k + 1) * RS] * xp[k + 1];
            a2 += wp[(size_t)(k + 2) * RS] * xp[k + 2];
            a3 += wp[(size_t)(k + 3) * RS] * xp[k + 3];
        }
        sh_part[tid] = (a0 + a1) + (a2 + a3);
    }
    __syncthreads();

    if (tid < RS) {
        const int gate = tid / JS, jj = tid % JS;
        const int grow = gate * NH + rh * JS + jj;
        sh_g[tid] = (((sh_part[tid] + sh_part[96 + tid])
                    + (sh_part[192 + tid] + sh_part[288 + tid]))
                   + ((sh_ph[tid] + sh_ph[96 + tid]) + sh_ph[192 + tid]))
                  + bsum[grow];
    }
    __syncthreads();
    if (tid < JS) {
        float gi = sh_g[tid], gf = sh_g[JS + tid];
        float gg = sh_g[2 * JS + tid], go = sh_g[3 * JS + tid];
        float c2 = sigmf(gf) * creg + sigmf(gi) * tanhf(gg);
        float h2 = sigmf(go) * tanhf(c2);
        cst[rh * JS + tid] = c2;
        h_w[rh * JS + tid] = h2;
        sh_h2[tid] = h2;
    }
    __syncthreads();
    if (tid < NL) {
        const float* wr = W_lin + (size_t)tid * 1152 + rh * JS;
        float a = 0.f;
        #pragma unroll
        for (int k = 0; k < JS; ++k) a += wr[k] * sh_h2[k];
        hWbp_w[rh * 36 + tid] = a;
    }
}

// ---- parallel log-softmax -------------------------------------------------
__global__ void k_post(float* __restrict__ out) {
    int row = blockIdx.x * 4 + (threadIdx.x >> 6);
    int lane = threadIdx.x & 63;
    if (row >= NB * NT) return;
    float* p = out + (size_t)row * NL;
    float x = (lane < NL) ? p[lane] : -INFINITY;
    float m = x;
    #pragma unroll
    for (int d = 32; d; d >>= 1) m = fmaxf(m, __shfl_xor(m, d));
    float e = (lane < NL) ? expf(x - m) : 0.f;
    float su = e;
    #pragma unroll
    for (int d = 32; d; d >>= 1) su += __shfl_xor(su, d);
    if (lane < NL) p[lane] = (x - m) - logf(su);
}

extern "C" void kernel_launch(void* const* d_in, const int* in_sizes, int n_in,
                              void* d_out, int out_size, void* d_ws, size_t ws_size,
                              hipStream_t stream) {
    const float* enc          = (const float*)d_in[0];
    const int*   char_sizes   = (const int*)d_in[1];
    const int*   label_is_sep = (const int*)d_in[2];
    const int*   label_pos_id = (const int*)d_in[3];
    const float* posEmb       = (const float*)d_in[4];
    const float* W_ih         = (const float*)d_in[5];
    const float* W_hh         = (const float*)d_in[6];
    const float* b_ih         = (const float*)d_in[7];
    const float* b_hh         = (const float*)d_in[8];
    const float* W_lin        = (const float*)d_in[9];
    const float* b_lin        = (const float*)d_in[10];
    const float* W_cmb        = (const float*)d_in[11];
    const float* b_cmb        = (const float*)d_in[12];
    float* out = (float*)d_out;
    float* ws  = (float*)d_ws;

    hipLaunchKernelGGL(k_prep, dim3(1024), dim3(256), 0, stream,
                       W_ih, W_hh, W_cmb, posEmb, ws);
    hipLaunchKernelGGL(k_encw, dim3((NB * NT * NL + 255) / 256), dim3(256), 0, stream,
                       enc, W_lin, ws);
    hipLaunchKernelGGL(k_encCmb, dim3(1024), dim3(384), 0, stream, enc, W_cmb, ws);
    hipLaunchKernelGGL(k_prefix, dim3((NB * NH + 255) / 256), dim3(256), 0, stream, ws);
    hipLaunchKernelGGL(k_init, dim3(1), dim3(1024), 0, stream,
                       b_ih, b_hh, W_lin, b_lin, ws);
    hipLaunchKernelGGL(k_fill, dim3((NB * NT * NL + 255) / 256), dim3(256), 0, stream, out);

    for (int r = 0; r < ROUNDS; ++r) {
        hipLaunchKernelGGL(k_round, dim3(256), dim3(384), 0, stream,
                           char_sizes, label_is_sep, label_pos_id,
                           W_lin, b_lin, b_cmb, ws, out, r & 1);
    }

    hipLaunchKernelGGL(k_post, dim3((NB * NT + 3) / 4), dim3(256), 0, stream, out);
}